// Round 10
// baseline (1196.098 us; speedup 1.0000x reference)
//
#include <hip/hip_runtime.h>
#include <hip/hip_cooperative_groups.h>
#include <cstdint>
#include <cstddef>
#include <cmath>

namespace cg = cooperative_groups;

#define D 128
#define NT 256

typedef short bf16x8 __attribute__((ext_vector_type(8)));
typedef float f32x4 __attribute__((ext_vector_type(4)));

__device__ __forceinline__ ushort f2b(float f) {
  uint x = __float_as_uint(f);
  uint r = ((x >> 16) & 1u) + 0x7fffu;   // round-to-nearest-even
  return (ushort)((x + r) >> 16);
}
__device__ __forceinline__ float b2f(ushort u) {
  return __uint_as_float(((uint)u) << 16);
}
// bijective 6-bit slot permutation (predict C->A epilogue bank spread)
__device__ __forceinline__ int pis(int l) {
  return (l & 0x20) | ((l & 3) << 3) | (((l >> 4) & 1) << 2) | ((l >> 2) & 3);
}

struct MegaP {
  const float* x;
  const int* src; const int* dst;
  const int* ps; const int* pd; const int* ns; const int* nd;
  const float *Ws0, *Wn0, *b0, *Ws1, *Wn1, *b1, *Ws2, *Wn2, *b2;
  const float *Wp0, *bp0, *Wp1, *bp1, *Wp2, *bp2;
  ushort *xb, *h1, *h2, *hn;
  ushort *BpL0, *BpL1, *BpL2, *BpP0, *BpP1;
  int *deg, *rowptr, *cursor, *partials, *csrc;
  float* outp;
  int N, E, P, CE;
  float pscale;
};

// ---------------- phase bodies (grid-stride on gridDim.x) ----------------
__device__ void prep_phase(const MegaP& P) {
  int TOTg = gridDim.x * NT;
  int gtid = blockIdx.x * NT + threadIdx.x;
  for (int i = gtid; i < P.N; i += TOTg) P.deg[i] = 0;
  int n8 = P.N * (D / 8);
  const float4* xin = (const float4*)P.x;
  for (int i = gtid; i < n8; i += TOTg) {
    float4 a = xin[i * 2], b = xin[i * 2 + 1];
    ushort4 o0 = {f2b(a.x), f2b(a.y), f2b(a.z), f2b(a.w)};
    ushort4 o1 = {f2b(b.x), f2b(b.y), f2b(b.z), f2b(b.w)};
    ((ushort4*)P.xb)[i * 2] = o0;
    ((ushort4*)P.xb)[i * 2 + 1] = o1;
  }
  for (int o = gtid; o < 131072; o += TOTg) {
    const float *W0, *W1; ushort* outw; int rel;
    if (o < 32768)       { W0 = P.Ws0; W1 = P.Wn0; outw = P.BpL0; rel = o; }
    else if (o < 65536)  { W0 = P.Ws1; W1 = P.Wn1; outw = P.BpL1; rel = o - 32768; }
    else if (o < 98304)  { W0 = P.Ws2; W1 = P.Wn2; outw = P.BpL2; rel = o - 65536; }
    else if (o < 114688) { W0 = P.Wp0; W1 = P.Wp0; outw = P.BpP0; rel = o - 98304; }
    else                 { W0 = P.Wp1; W1 = P.Wp1; outw = P.BpP1; rel = o - 114688; }
    int j = rel & 7, lane = (rel >> 3) & 63, t = (rel >> 9) & 7, ks = rel >> 12;
    int k = ks * 32 + ((lane >> 4) * 8) + j;
    int n = t * 16 + (lane & 15);
    const float* W = (k < 128) ? W0 : W1;
    int kk = (k < 128) ? k : k - 128;
    outw[rel] = f2b(W[(size_t)kk * D + n]);
  }
}

__device__ void degree_phase(const MegaP& P) {
  int part = blockIdx.x & 7, chunk = blockIdx.x >> 3;
  long base = (long)chunk * P.CE;
  for (int i = threadIdx.x; i < P.CE; i += NT) {
    long e = base + i;
    if (e < P.E) {
      int d = P.dst[e];
      int pp = (int)((float)d * P.pscale); if (pp > 7) pp = 7;
      if (pp == part) atomicAdd(&P.deg[d], 1);
    }
  }
}

__device__ void scanA_phase(const MegaP& P, int* sint) {
  int tid = threadIdx.x;
  int nchunk = (P.N + 1023) >> 10;
  for (int c = blockIdx.x; c < nchunk; c += gridDim.x) {
    int basei = c << 10;
    int sum = 0;
    #pragma unroll
    for (int k = 0; k < 4; ++k) {
      int idx = basei + tid * 4 + k;
      if (idx < P.N) sum += P.deg[idx];
    }
    sint[tid] = sum; __syncthreads();
    for (int ofs = 128; ofs > 0; ofs >>= 1) {
      if (tid < ofs) sint[tid] += sint[tid + ofs];
      __syncthreads();
    }
    if (tid == 0) P.partials[c] = sint[0];
    __syncthreads();
  }
}

__device__ void scanB_phase(const MegaP& P, int* sint) {
  int tid = threadIdx.x;
  int nchunk = (P.N + 1023) >> 10;
  if (blockIdx.x == 0) {
    int v = (tid < nchunk) ? P.partials[tid] : 0;
    sint[tid] = v; __syncthreads();
    for (int ofs = 1; ofs < 256; ofs <<= 1) {
      int t = (tid >= ofs) ? sint[tid - ofs] : 0;
      __syncthreads();
      sint[tid] += t;
      __syncthreads();
    }
    if (tid < nchunk) P.partials[tid] = sint[tid] - v;
  }
}

__device__ void scanC_phase(const MegaP& P, int* sint) {
  int tid = threadIdx.x;
  int nchunk = (P.N + 1023) >> 10;
  for (int c = blockIdx.x; c < nchunk; c += gridDim.x) {
    int basei = c << 10;
    int v[4]; int local = 0;
    #pragma unroll
    for (int k = 0; k < 4; ++k) {
      int idx = basei + tid * 4 + k;
      v[k] = (idx < P.N) ? P.deg[idx] : 0;
      local += v[k];
    }
    sint[tid] = local; __syncthreads();
    for (int ofs = 1; ofs < 256; ofs <<= 1) {
      int t = (tid >= ofs) ? sint[tid - ofs] : 0;
      __syncthreads();
      sint[tid] += t;
      __syncthreads();
    }
    int run = P.partials[c] + sint[tid] - local;   // exclusive prefix
    #pragma unroll
    for (int k = 0; k < 4; ++k) {
      int idx = basei + tid * 4 + k;
      if (idx < P.N) { P.rowptr[idx] = run; P.cursor[idx] = run; }
      run += v[k];
    }
    __syncthreads();
  }
  if (blockIdx.x == 0 && tid == 0) P.rowptr[P.N] = P.E;
}

__device__ void fill_phase(const MegaP& P) {
  int part = blockIdx.x & 7, chunk = blockIdx.x >> 3;
  long base = (long)chunk * P.CE;
  for (int i = threadIdx.x; i < P.CE; i += NT) {
    long e = base + i;
    if (e < P.E) {
      int d = P.dst[e];
      int pp = (int)((float)d * P.pscale); if (pp > 7) pp = 7;
      if (pp == part) {
        int s = P.src[e];
        int pos = atomicAdd(&P.cursor[d], 1);
        P.csrc[pos] = s;
      }
    }
  }
}

__device__ void agg_phase(const ushort* __restrict__ h, const int* __restrict__ rowptr,
    const int* __restrict__ csrc, ushort* __restrict__ hn, int N) {
  int tid = threadIdx.x, lane = tid & 63;
  int g = lane >> 4, sub = lane & 15, gb = g << 4;
  int w0 = (int)((blockIdx.x * NT + tid) >> 6);
  int Q = (N + 3) >> 2, W = gridDim.x * 4;
  const ushort* hb = h + sub * 8;
  for (int q = w0; q < Q; q += W) {
    int node = q * 4 + g;
    int beg = 0, end = 0;
    if (node < N) { beg = rowptr[node]; end = rowptr[node + 1]; }
    int dg = end - beg;
    int dd = dg < 16 ? dg : 16;
    int i0 = beg + sub;
    int idxv = (i0 < end) ? csrc[i0] : 0;
    float f[8] = {0.f, 0.f, 0.f, 0.f, 0.f, 0.f, 0.f, 0.f};
    for (int e = 0; e < dd; e += 2) {
      int s0 = __shfl(idxv, gb + e);
      int s1 = __shfl(idxv, gb + e + 1);
      bf16x8 r0 = *(const bf16x8*)(hb + (size_t)s0 * D);
      if (e + 1 < dd) {
        bf16x8 r1 = *(const bf16x8*)(hb + (size_t)s1 * D);
        #pragma unroll
        for (int q2 = 0; q2 < 8; ++q2)
          f[q2] += b2f((ushort)r0[q2]) + b2f((ushort)r1[q2]);
      } else {
        #pragma unroll
        for (int q2 = 0; q2 < 8; ++q2) f[q2] += b2f((ushort)r0[q2]);
      }
    }
    for (int i = beg + 16; i < end; ++i) {   // rare deg>16 tail
      int s = csrc[i];
      bf16x8 v = *(const bf16x8*)(hb + (size_t)s * D);
      #pragma unroll
      for (int q2 = 0; q2 < 8; ++q2) f[q2] += b2f((ushort)v[q2]);
    }
    if (node < N) {
      float inv = (dg > 0) ? (1.0f / (float)dg) : 0.0f;
      bf16x8 o;
      #pragma unroll
      for (int q2 = 0; q2 < 8; ++q2) o[q2] = (short)f2b(f[q2] * inv);
      *(bf16x8*)(hn + (size_t)node * D + sub * 8) = o;
    }
  }
}

__device__ void gemm_phase(const ushort* __restrict__ A, const ushort* __restrict__ An,
    const ushort* __restrict__ Bp, const float* __restrict__ bias,
    ushort* __restrict__ out, int N, int do_relu) {
  int tid = threadIdx.x, wave = tid >> 6, lane = tid & 63;
  int m = lane & 15, kg = lane >> 4;
  int tiles = (N + 63) >> 6;
  for (int t0 = blockIdx.x; t0 < tiles; t0 += gridDim.x) {
    int row0 = t0 * 64 + wave * 16;
    int ar = row0 + m; if (ar >= N) ar = N - 1;
    const ushort* a_self = A  + (size_t)ar * D + kg * 8;
    const ushort* a_nei  = An + (size_t)ar * D + kg * 8;
    f32x4 acc[8];
    #pragma unroll
    for (int t = 0; t < 8; ++t) acc[t] = f32x4{0.f, 0.f, 0.f, 0.f};
    #pragma unroll
    for (int ks = 0; ks < 8; ++ks) {
      const ushort* ap = (ks < 4) ? a_self : a_nei;
      bf16x8 af = *(const bf16x8*)(ap + (ks & 3) * 32);
      const ushort* bb = Bp + (size_t)ks * 4096 + lane * 8;
      #pragma unroll
      for (int t = 0; t < 8; ++t)
        acc[t] = __builtin_amdgcn_mfma_f32_16x16x32_bf16(af, *(const bf16x8*)(bb + t * 512), acc[t], 0, 0, 0);
    }
    #pragma unroll
    for (int t = 0; t < 8; ++t) {
      int c = t * 16 + m;
      float bv = bias[c];
      #pragma unroll
      for (int i = 0; i < 4; ++i) {
        int r = row0 + kg * 4 + i;
        float v = acc[t][i] + bv;
        if (do_relu) v = fmaxf(v, 0.f);
        if (r < N) out[(size_t)r * D + c] = f2b(v);
      }
    }
  }
}

__device__ void pred_phase(ushort* sb, const ushort* __restrict__ h,
    const int* __restrict__ ps, const int* __restrict__ pd,
    const int* __restrict__ ns, const int* __restrict__ nd,
    const ushort* __restrict__ Bp0, const float* __restrict__ bp0,
    const ushort* __restrict__ Bp1, const float* __restrict__ bp1,
    const float* __restrict__ Wp2, const float* __restrict__ bp2,
    float* __restrict__ outp, int P) {
  int tid = threadIdx.x, wave = tid >> 6, lane = tid & 63;
  int m = lane & 15, kg = lane >> 4;
  int pl = pis(lane);
  ushort* zp = sb + wave * 2048;
  int pb = (P + 63) >> 6;
  int tiles = 2 * pb;
  for (int bt = blockIdx.x; bt < tiles; bt += gridDim.x) {
    int bi = bt; const int* sidx; const int* didx; float* op;
    if (bi >= pb) { sidx = ns; didx = nd; op = outp + P; bi -= pb; }
    else          { sidx = ps; didx = pd; op = outp; }
    int pair0 = bi * 64 + wave * 16;
    int prow = pair0 + m; int pr = (prow < P) ? prow : P - 1;
    int si = sidx[pr], di = didx[pr];
    const ushort* hs = h + (size_t)si * D + kg * 8;
    const ushort* hd = h + (size_t)di * D + kg * 8;
    f32x4 acc[8];
    #pragma unroll
    for (int t = 0; t < 8; ++t) acc[t] = f32x4{0.f, 0.f, 0.f, 0.f};
    #pragma unroll
    for (int ks = 0; ks < 4; ++ks) {
      bf16x8 as8 = *(const bf16x8*)(hs + ks * 32);
      bf16x8 ad8 = *(const bf16x8*)(hd + ks * 32);
      bf16x8 af;
      #pragma unroll
      for (int j = 0; j < 8; ++j) {
        float p = b2f((ushort)as8[j]) * b2f((ushort)ad8[j]);
        af[j] = (short)f2b(p);
      }
      const ushort* bb = Bp0 + (size_t)ks * 4096 + lane * 8;
      #pragma unroll
      for (int t = 0; t < 8; ++t)
        acc[t] = __builtin_amdgcn_mfma_f32_16x16x32_bf16(af, *(const bf16x8*)(bb + t * 512), acc[t], 0, 0, 0);
    }
    #pragma unroll
    for (int t = 0; t < 8; ++t) {
      int c = t * 16 + m;
      float bv = bp0[c];
      int ks2 = c >> 5, kg2 = (c >> 3) & 3, j2 = c & 7;
      #pragma unroll
      for (int i = 0; i < 4; ++i) {
        float v = fmaxf(acc[t][i] + bv, 0.f);
        int l2 = kg2 * 16 + kg * 4 + i;
        zp[ks2 * 512 + pis(l2) * 8 + j2] = f2b(v);
      }
    }
    __syncthreads();
    #pragma unroll
    for (int t = 0; t < 8; ++t) acc[t] = f32x4{0.f, 0.f, 0.f, 0.f};
    #pragma unroll
    for (int ks = 0; ks < 4; ++ks) {
      bf16x8 af = *(const bf16x8*)(zp + ks * 512 + pl * 8);
      const ushort* bb = Bp1 + (size_t)ks * 4096 + lane * 8;
      #pragma unroll
      for (int t = 0; t < 8; ++t)
        acc[t] = __builtin_amdgcn_mfma_f32_16x16x32_bf16(af, *(const bf16x8*)(bb + t * 512), acc[t], 0, 0, 0);
    }
    float p0[4] = {0.f, 0.f, 0.f, 0.f}, p1[4] = {0.f, 0.f, 0.f, 0.f};
    #pragma unroll
    for (int t = 0; t < 8; ++t) {
      int c = t * 16 + m;
      float bv = bp1[c];
      float wa = Wp2[(size_t)c * 2], wb = Wp2[(size_t)c * 2 + 1];
      #pragma unroll
      for (int i = 0; i < 4; ++i) {
        float z = fmaxf(acc[t][i] + bv, 0.f);
        p0[i] += z * wa;
        p1[i] += z * wb;
      }
    }
    #pragma unroll
    for (int msk = 1; msk <= 8; msk <<= 1) {
      #pragma unroll
      for (int i = 0; i < 4; ++i) {
        p0[i] += __shfl_xor(p0[i], msk);
        p1[i] += __shfl_xor(p1[i], msk);
      }
    }
    if (m == 0) {
      float c0 = bp2[0], c1 = bp2[1];
      #pragma unroll
      for (int i = 0; i < 4; ++i) {
        int r = pair0 + kg * 4 + i;
        if (r < P) {
          float l0 = p0[i] + c0, l1 = p1[i] + c1;
          op[r] = 1.0f / (1.0f + expf(l0 - l1));
        }
      }
    }
    __syncthreads();
  }
}

// ======================= cooperative mega kernel =======================
__global__ __launch_bounds__(NT) void k_mega(MegaP P) {
  cg::grid_group grid = cg::this_grid();
  __shared__ __align__(16) ushort sbuf[8192];   // 16 KB
  int* sint = (int*)sbuf;
  prep_phase(P);                               grid.sync();
  degree_phase(P);                             grid.sync();
  scanA_phase(P, sint);                        grid.sync();
  scanB_phase(P, sint);                        grid.sync();
  scanC_phase(P, sint);                        grid.sync();
  fill_phase(P);                               grid.sync();
  agg_phase(P.xb, P.rowptr, P.csrc, P.hn, P.N);        grid.sync();
  gemm_phase(P.xb, P.hn, P.BpL0, P.b0, P.h1, P.N, 1);  grid.sync();
  agg_phase(P.h1, P.rowptr, P.csrc, P.hn, P.N);        grid.sync();
  gemm_phase(P.h1, P.hn, P.BpL1, P.b1, P.h2, P.N, 1);  grid.sync();
  agg_phase(P.h2, P.rowptr, P.csrc, P.hn, P.N);        grid.sync();
  gemm_phase(P.h2, P.hn, P.BpL2, P.b2, P.xb, P.N, 0);  grid.sync();
  pred_phase(sbuf, P.xb, P.ps, P.pd, P.ns, P.nd,
             P.BpP0, P.bp0, P.BpP1, P.bp1, P.Wp2, P.bp2, P.outp, P.P);
}

// ======================= fallback wrappers =======================
__global__ __launch_bounds__(NT) void k_prep_w(MegaP P)   { prep_phase(P); }
__global__ __launch_bounds__(NT) void k_degree_w(MegaP P) { degree_phase(P); }
__global__ __launch_bounds__(NT) void k_scanA_w(MegaP P) {
  __shared__ int s[NT]; scanA_phase(P, s);
}
__global__ __launch_bounds__(NT) void k_scanB_w(MegaP P) {
  __shared__ int s[NT]; scanB_phase(P, s);
}
__global__ __launch_bounds__(NT) void k_scanC_w(MegaP P) {
  __shared__ int s[NT]; scanC_phase(P, s);
}
__global__ __launch_bounds__(NT) void k_fill_w(MegaP P)   { fill_phase(P); }
__global__ __launch_bounds__(NT) void k_agg_w(const ushort* h, const int* rowptr,
    const int* csrc, ushort* hn, int N) { agg_phase(h, rowptr, csrc, hn, N); }
__global__ __launch_bounds__(NT) void k_gemm_w(const ushort* A, const ushort* An,
    const ushort* Bp, const float* bias, ushort* out, int N, int do_relu) {
  gemm_phase(A, An, Bp, bias, out, N, do_relu);
}
__global__ __launch_bounds__(NT) void k_pred_w(const ushort* h,
    const int* ps, const int* pd, const int* ns, const int* nd,
    const ushort* Bp0, const float* bp0, const ushort* Bp1, const float* bp1,
    const float* Wp2, const float* bp2, float* outp, int P) {
  __shared__ __align__(16) ushort sb[8192];
  pred_phase(sb, h, ps, pd, ns, nd, Bp0, bp0, Bp1, bp1, Wp2, bp2, outp, P);
}

// ======================= launch =======================
extern "C" void kernel_launch(void* const* d_in, const int* in_sizes, int n_in,
                              void* d_out, int out_size, void* d_ws, size_t ws_size,
                              hipStream_t stream) {
  MegaP mp;
  mp.x   = (const float*)d_in[0];
  mp.src = (const int*)d_in[1];
  mp.dst = (const int*)d_in[2];
  mp.ps  = (const int*)d_in[3];
  mp.pd  = (const int*)d_in[4];
  mp.ns  = (const int*)d_in[5];
  mp.nd  = (const int*)d_in[6];
  mp.Ws0 = (const float*)d_in[7];  mp.Wn0 = (const float*)d_in[8];  mp.b0 = (const float*)d_in[9];
  mp.Ws1 = (const float*)d_in[10]; mp.Wn1 = (const float*)d_in[11]; mp.b1 = (const float*)d_in[12];
  mp.Ws2 = (const float*)d_in[13]; mp.Wn2 = (const float*)d_in[14]; mp.b2 = (const float*)d_in[15];
  mp.Wp0 = (const float*)d_in[16]; mp.bp0 = (const float*)d_in[17];
  mp.Wp1 = (const float*)d_in[18]; mp.bp1 = (const float*)d_in[19];
  mp.Wp2 = (const float*)d_in[20]; mp.bp2 = (const float*)d_in[21];
  const int N = in_sizes[0] / D;
  const int E = in_sizes[1];
  const int P = in_sizes[3];
  mp.N = N; mp.E = E; mp.P = P;
  mp.pscale = 8.0f / (float)N;
  mp.outp = (float*)d_out;

  char* ws = (char*)d_ws;
  size_t off = 0;
  auto alloc = [&](size_t bytes) -> void* {
    void* p = ws + off;
    off += (bytes + 255) & ~(size_t)255;
    return p;
  };
  mp.xb   = (ushort*)alloc((size_t)N * D * 2);
  mp.h1   = (ushort*)alloc((size_t)N * D * 2);
  mp.h2   = (ushort*)alloc((size_t)N * D * 2);
  mp.hn   = (ushort*)alloc((size_t)N * D * 2);
  mp.BpL0 = (ushort*)alloc(256 * D * 2);
  mp.BpL1 = (ushort*)alloc(256 * D * 2);
  mp.BpL2 = (ushort*)alloc(256 * D * 2);
  mp.BpP0 = (ushort*)alloc(128 * D * 2);
  mp.BpP1 = (ushort*)alloc(128 * D * 2);
  mp.deg     = (int*)alloc((size_t)N * 4);
  mp.rowptr  = (int*)alloc((size_t)(N + 1) * 4);
  mp.cursor  = (int*)alloc((size_t)N * 4);
  mp.partials= (int*)alloc(1024 * 4);
  mp.csrc    = (int*)alloc((size_t)E * 4);
  (void)ws_size; (void)n_in; (void)out_size;

  // real co-residency for the mega kernel (host query; graph-capture safe)
  int occ = 0;
  hipError_t oe = hipOccupancyMaxActiveBlocksPerMultiprocessor(
      &occ, (const void*)k_mega, NT, 0);
  int NBe = ((oe == hipSuccess && occ > 0) ? occ : 1) * 256;
  if (NBe > 1024) NBe = 1024;
  mp.CE = (E + (NBe / 8) - 1) / (NBe / 8);

  void* kargs[] = { (void*)&mp };
  hipError_t le = hipLaunchCooperativeKernel((const void*)k_mega, dim3(NBe),
                                             dim3(NT), kargs, 0, stream);
  if (le != hipSuccess) {
    // ---- fallback: same phase bodies as ordinary kernels (12 launches) ----
    int aggb = (N + 15) / 16;        // 4 nodes/wave * 4 waves
    int gemb = (N + 63) / 64;
    int pb2  = 2 * ((P + 63) / 64);
    k_prep_w  <<<NBe, NT, 0, stream>>>(mp);
    k_degree_w<<<NBe, NT, 0, stream>>>(mp);
    k_scanA_w <<<256, NT, 0, stream>>>(mp);
    k_scanB_w <<<1,   NT, 0, stream>>>(mp);
    k_scanC_w <<<256, NT, 0, stream>>>(mp);
    k_fill_w  <<<NBe, NT, 0, stream>>>(mp);
    k_agg_w <<<aggb, NT, 0, stream>>>(mp.xb, mp.rowptr, mp.csrc, mp.hn, N);
    k_gemm_w<<<gemb, NT, 0, stream>>>(mp.xb, mp.hn, mp.BpL0, mp.b0, mp.h1, N, 1);
    k_agg_w <<<aggb, NT, 0, stream>>>(mp.h1, mp.rowptr, mp.csrc, mp.hn, N);
    k_gemm_w<<<gemb, NT, 0, stream>>>(mp.h1, mp.hn, mp.BpL1, mp.b1, mp.h2, N, 1);
    k_agg_w <<<aggb, NT, 0, stream>>>(mp.h2, mp.rowptr, mp.csrc, mp.hn, N);
    k_gemm_w<<<gemb, NT, 0, stream>>>(mp.h2, mp.hn, mp.BpL2, mp.b2, mp.xb, N, 0);
    k_pred_w<<<pb2, NT, 0, stream>>>(mp.xb, mp.ps, mp.pd, mp.ns, mp.nd,
                                     mp.BpP0, mp.bp0, mp.BpP1, mp.bp1,
                                     mp.Wp2, mp.bp2, mp.outp, P);
  }
}

// Round 11
// 467.484 us; speedup vs baseline: 2.5586x; 2.5586x over previous
//
#include <hip/hip_runtime.h>
#include <cstdint>
#include <cstddef>
#include <cmath>

#define D 128

typedef short bf16x8 __attribute__((ext_vector_type(8)));
typedef float f32x4 __attribute__((ext_vector_type(4)));

__device__ __forceinline__ ushort f2b(float f) {
  uint x = __float_as_uint(f);
  uint r = ((x >> 16) & 1u) + 0x7fffu;   // round-to-nearest-even
  return (ushort)((x + r) >> 16);
}
__device__ __forceinline__ float b2f(ushort u) {
  return __uint_as_float(((uint)u) << 16);
}
// bijective 6-bit slot permutation (predict C->A epilogue bank spread)
__device__ __forceinline__ int pis(int l) {
  return (l & 0x20) | ((l & 3) << 3) | (((l >> 4) & 1) << 2) | ((l >> 2) & 3);
}

// ============ prep: zero deg + x->bf16 + pack all weights (1 kernel) ============
__global__ __launch_bounds__(256) void k_prep(
    const float* __restrict__ x, ushort* __restrict__ xb,
    const float* __restrict__ Ws0, const float* __restrict__ Wn0,
    const float* __restrict__ Ws1, const float* __restrict__ Wn1,
    const float* __restrict__ Ws2, const float* __restrict__ Wn2,
    const float* __restrict__ Wp0, const float* __restrict__ Wp1,
    ushort* __restrict__ BpL0, ushort* __restrict__ BpL1, ushort* __restrict__ BpL2,
    ushort* __restrict__ BpP0, ushort* __restrict__ BpP1,
    int* __restrict__ deg, int N) {
  int TOTg = gridDim.x * 256;
  int gtid = blockIdx.x * 256 + threadIdx.x;
  for (int i = gtid; i < N; i += TOTg) deg[i] = 0;
  int n8 = N * (D / 8);
  const float4* xin = (const float4*)x;
  for (int i = gtid; i < n8; i += TOTg) {
    float4 a = xin[i * 2], b = xin[i * 2 + 1];
    ushort4 o0 = {f2b(a.x), f2b(a.y), f2b(a.z), f2b(a.w)};
    ushort4 o1 = {f2b(b.x), f2b(b.y), f2b(b.z), f2b(b.w)};
    ((ushort4*)xb)[i * 2] = o0;
    ((ushort4*)xb)[i * 2 + 1] = o1;
  }
  for (int o = gtid; o < 131072; o += TOTg) {
    const float *W0, *W1; ushort* outw; int rel;
    if (o < 32768)       { W0 = Ws0; W1 = Wn0; outw = BpL0; rel = o; }
    else if (o < 65536)  { W0 = Ws1; W1 = Wn1; outw = BpL1; rel = o - 32768; }
    else if (o < 98304)  { W0 = Ws2; W1 = Wn2; outw = BpL2; rel = o - 65536; }
    else if (o < 114688) { W0 = Wp0; W1 = Wp0; outw = BpP0; rel = o - 98304; }
    else                 { W0 = Wp1; W1 = Wp1; outw = BpP1; rel = o - 114688; }
    int j = rel & 7, lane = (rel >> 3) & 63, t = (rel >> 9) & 7, ks = rel >> 12;
    int k = ks * 32 + ((lane >> 4) * 8) + j;
    int n = t * 16 + (lane & 15);
    const float* W = (k < 128) ? W0 : W1;
    int kk = (k < 128) ? k : k - 128;
    outw[rel] = f2b(W[(size_t)kk * D + n]);
  }
}

// ======================= CSR build (XCD-partitioned) =======================
__global__ __launch_bounds__(256) void k_degree_p(const int* __restrict__ dst, int E,
    int* __restrict__ deg, float scale, int CE) {
  int part = blockIdx.x & 7, chunk = blockIdx.x >> 3;
  long base = (long)chunk * CE;
  for (int i = threadIdx.x; i < CE; i += 256) {
    long e = base + i;
    if (e < E) {
      int d = dst[e];
      int p = (int)((float)d * scale); if (p > 7) p = 7;
      if (p == part) atomicAdd(&deg[d], 1);
    }
  }
}

__global__ __launch_bounds__(256) void k_fill_p(const int* __restrict__ src,
    const int* __restrict__ dst, int E, int* __restrict__ cursor,
    int* __restrict__ csrc, float scale, int CE) {
  int part = blockIdx.x & 7, chunk = blockIdx.x >> 3;
  long base = (long)chunk * CE;
  for (int i = threadIdx.x; i < CE; i += 256) {
    long e = base + i;
    if (e < E) {
      int d = dst[e];
      int p = (int)((float)d * scale); if (p > 7) p = 7;
      if (p == part) {
        int s = src[e];
        int pos = atomicAdd(&cursor[d], 1);
        csrc[pos] = s;
      }
    }
  }
}

#define SCAN_T 256
#define SCAN_E 4
#define SCAN_CHUNK (SCAN_T * SCAN_E)

__global__ void k_scan_partial(const int* __restrict__ deg, int n, int* __restrict__ part) {
  __shared__ int s[SCAN_T];
  int base = blockIdx.x * SCAN_CHUNK;
  int sum = 0;
  for (int i = 0; i < SCAN_E; ++i) {
    int idx = base + (int)threadIdx.x * SCAN_E + i;
    if (idx < n) sum += deg[idx];
  }
  s[threadIdx.x] = sum; __syncthreads();
  for (int ofs = SCAN_T / 2; ofs > 0; ofs >>= 1) {
    if ((int)threadIdx.x < ofs) s[threadIdx.x] += s[threadIdx.x + ofs];
    __syncthreads();
  }
  if (threadIdx.x == 0) part[blockIdx.x] = s[0];
}

__global__ void k_scan_part_ex(int* __restrict__ part, int nb) {
  __shared__ int s[1024];
  int v = ((int)threadIdx.x < nb) ? part[threadIdx.x] : 0;
  s[threadIdx.x] = v; __syncthreads();
  for (int ofs = 1; ofs < 1024; ofs <<= 1) {
    int t = ((int)threadIdx.x >= ofs) ? s[threadIdx.x - ofs] : 0;
    __syncthreads();
    s[threadIdx.x] += t;
    __syncthreads();
  }
  if ((int)threadIdx.x < nb) part[threadIdx.x] = s[threadIdx.x] - v;  // exclusive
}

__global__ void k_scan_final(const int* __restrict__ deg, int n, const int* __restrict__ part,
                             int* __restrict__ rowptr, int* __restrict__ cursor, int E) {
  __shared__ int s[SCAN_T];
  int base = blockIdx.x * SCAN_CHUNK;
  int v[SCAN_E]; int local = 0;
  for (int i = 0; i < SCAN_E; ++i) {
    int idx = base + (int)threadIdx.x * SCAN_E + i;
    v[i] = (idx < n) ? deg[idx] : 0;
    local += v[i];
  }
  s[threadIdx.x] = local; __syncthreads();
  for (int ofs = 1; ofs < SCAN_T; ofs <<= 1) {
    int t = ((int)threadIdx.x >= ofs) ? s[threadIdx.x - ofs] : 0;
    __syncthreads();
    s[threadIdx.x] += t;
    __syncthreads();
  }
  int run = part[blockIdx.x] + s[threadIdx.x] - local;  // exclusive prefix
  for (int i = 0; i < SCAN_E; ++i) {
    int idx = base + (int)threadIdx.x * SCAN_E + i;
    if (idx < n) { rowptr[idx] = run; cursor[idx] = run; }
    run += v[i];
  }
  if (blockIdx.x == 0 && threadIdx.x == 0) rowptr[n] = E;
}

// ======================= standalone mean aggregation ================
// 1 node per 16-lane group (4 nodes/wave) -> 25k waves. Index-prefetch +
// shfl-addressed row loop unrolled x4 (4 rows issued per stall window).
__global__ __launch_bounds__(256) void k_aggregate2(const ushort* __restrict__ h,
    const int* __restrict__ rowptr, const int* __restrict__ csrc,
    ushort* __restrict__ hn, int N) {
  int tid = threadIdx.x, lane = tid & 63;
  int wid = (int)((blockIdx.x * 256 + tid) >> 6);
  int g = lane >> 4, sub = lane & 15, gb = g << 4;
  int node = wid * 4 + g;
  if (node >= N) return;
  int beg = rowptr[node], end = rowptr[node + 1];
  int dg = end - beg;
  int dd = dg < 16 ? dg : 16;
  int i0 = beg + sub;
  int idxv = (i0 < end) ? csrc[i0] : 0;
  const ushort* hb = h + sub * 8;
  float f[8] = {0.f, 0.f, 0.f, 0.f, 0.f, 0.f, 0.f, 0.f};
  for (int e = 0; e < dd; e += 4) {
    int s0 = __shfl(idxv, gb + e);
    int s1 = __shfl(idxv, gb + e + 1);
    int s2 = __shfl(idxv, gb + e + 2);
    int s3 = __shfl(idxv, gb + e + 3);
    int cnt = dd - e;                      // group-uniform
    bf16x8 r0 = *(const bf16x8*)(hb + (size_t)s0 * D);
    if (cnt > 1) {
      bf16x8 r1 = *(const bf16x8*)(hb + (size_t)s1 * D);
      if (cnt > 2) {
        bf16x8 r2 = *(const bf16x8*)(hb + (size_t)s2 * D);
        if (cnt > 3) {
          bf16x8 r3 = *(const bf16x8*)(hb + (size_t)s3 * D);
          #pragma unroll
          for (int q = 0; q < 8; ++q)
            f[q] += (b2f((ushort)r0[q]) + b2f((ushort)r1[q]))
                  + (b2f((ushort)r2[q]) + b2f((ushort)r3[q]));
        } else {
          #pragma unroll
          for (int q = 0; q < 8; ++q)
            f[q] += b2f((ushort)r0[q]) + b2f((ushort)r1[q]) + b2f((ushort)r2[q]);
        }
      } else {
        #pragma unroll
        for (int q = 0; q < 8; ++q)
          f[q] += b2f((ushort)r0[q]) + b2f((ushort)r1[q]);
      }
    } else {
      #pragma unroll
      for (int q = 0; q < 8; ++q) f[q] += b2f((ushort)r0[q]);
    }
  }
  for (int i = beg + 16; i < end; ++i) {   // rare deg>16 tail
    int s = csrc[i];
    bf16x8 v = *(const bf16x8*)(hb + (size_t)s * D);
    #pragma unroll
    for (int q = 0; q < 8; ++q) f[q] += b2f((ushort)v[q]);
  }
  float inv = (dg > 0) ? (1.0f / (float)dg) : 0.0f;
  bf16x8 o;
  #pragma unroll
  for (int q = 0; q < 8; ++q) o[q] = (short)f2b(f[q] * inv);
  *(bf16x8*)(hn + (size_t)node * D + sub * 8) = o;
}

// ======================= SAGE layer GEMM (MFMA, no LDS) =======================
__global__ __launch_bounds__(256) void k_gemm_mfma(
    const ushort* __restrict__ A, const ushort* __restrict__ An,
    const ushort* __restrict__ Bp, const float* __restrict__ bias,
    ushort* __restrict__ out, int N, int do_relu) {
  int tid = threadIdx.x;
  int wave = tid >> 6, lane = tid & 63;
  int m = lane & 15, kg = lane >> 4;
  int row0 = blockIdx.x * 64 + wave * 16;
  int ar = row0 + m; if (ar >= N) ar = N - 1;   // clamp reads; stores guarded
  const ushort* a_self = A  + (size_t)ar * D + kg * 8;
  const ushort* a_nei  = An + (size_t)ar * D + kg * 8;
  f32x4 acc[8];
  #pragma unroll
  for (int t = 0; t < 8; ++t) acc[t] = f32x4{0.f, 0.f, 0.f, 0.f};
  #pragma unroll
  for (int ks = 0; ks < 8; ++ks) {
    const ushort* ap = (ks < 4) ? a_self : a_nei;
    bf16x8 af = *(const bf16x8*)(ap + (ks & 3) * 32);
    const ushort* bb = Bp + (size_t)ks * 4096 + lane * 8;
    #pragma unroll
    for (int t = 0; t < 8; ++t)
      acc[t] = __builtin_amdgcn_mfma_f32_16x16x32_bf16(af, *(const bf16x8*)(bb + t * 512), acc[t], 0, 0, 0);
  }
  #pragma unroll
  for (int t = 0; t < 8; ++t) {
    int c = t * 16 + m;
    float bv = bias[c];
    #pragma unroll
    for (int i = 0; i < 4; ++i) {
      int r = row0 + kg * 4 + i;
      float v = acc[t][i] + bv;
      if (do_relu) v = fmaxf(v, 0.f);
      if (r < N) out[(size_t)r * D + c] = f2b(v);
    }
  }
}

// ======================= fused predictor MLP (MFMA, pos+neg merged) ============
__global__ __launch_bounds__(256) void k_predict_mfma(
    const ushort* __restrict__ h,
    const int* __restrict__ ps, const int* __restrict__ pd,
    const int* __restrict__ ns, const int* __restrict__ nd,
    const ushort* __restrict__ Bp0, const float* __restrict__ bp0,
    const ushort* __restrict__ Bp1, const float* __restrict__ bp1,
    const float* __restrict__ Wp2, const float* __restrict__ bp2,
    float* __restrict__ outp, int P, int pb) {
  __shared__ __align__(16) ushort z1p[4][2048];  // per-wave A-frag-packed z1
  int bi = blockIdx.x;
  const int* sidx; const int* didx; float* op;
  if (bi >= pb) { sidx = ns; didx = nd; op = outp + P; bi -= pb; }
  else          { sidx = ps; didx = pd; op = outp; }
  int tid = threadIdx.x;
  int wave = tid >> 6, lane = tid & 63;
  int m = lane & 15, kg = lane >> 4;
  int pl = pis(lane);
  int pair0 = bi * 64 + wave * 16;
  int prow = pair0 + m; int pr = (prow < P) ? prow : P - 1;
  int si = sidx[pr], di = didx[pr];
  const ushort* hs = h + (size_t)si * D + kg * 8;
  const ushort* hd = h + (size_t)di * D + kg * 8;
  f32x4 acc[8];
  #pragma unroll
  for (int t = 0; t < 8; ++t) acc[t] = f32x4{0.f, 0.f, 0.f, 0.f};
  // ---- GEMM1: z = hs*hd ; acc = z @ Wp0 ----
  #pragma unroll
  for (int ks = 0; ks < 4; ++ks) {
    bf16x8 as8 = *(const bf16x8*)(hs + ks * 32);
    bf16x8 ad8 = *(const bf16x8*)(hd + ks * 32);
    bf16x8 af;
    #pragma unroll
    for (int j = 0; j < 8; ++j) {
      float p = b2f((ushort)as8[j]) * b2f((ushort)ad8[j]);
      af[j] = (short)f2b(p);
    }
    const ushort* bb = Bp0 + (size_t)ks * 4096 + lane * 8;
    #pragma unroll
    for (int t = 0; t < 8; ++t)
      acc[t] = __builtin_amdgcn_mfma_f32_16x16x32_bf16(af, *(const bf16x8*)(bb + t * 512), acc[t], 0, 0, 0);
  }
  // ---- epilogue1: relu(acc + bp0) -> LDS, A-frag order, pi-swizzled slots ----
  ushort* zp = &z1p[wave][0];
  #pragma unroll
  for (int t = 0; t < 8; ++t) {
    int c = t * 16 + m;
    float bv = bp0[c];
    int ks2 = c >> 5, kg2 = (c >> 3) & 3, j2 = c & 7;
    #pragma unroll
    for (int i = 0; i < 4; ++i) {
      float v = fmaxf(acc[t][i] + bv, 0.f);
      int l2 = kg2 * 16 + kg * 4 + i;     // consumer lane
      zp[ks2 * 512 + pis(l2) * 8 + j2] = f2b(v);
    }
  }
  __syncthreads();
  // ---- GEMM2: acc = z1 @ Wp1 ----
  #pragma unroll
  for (int t = 0; t < 8; ++t) acc[t] = f32x4{0.f, 0.f, 0.f, 0.f};
  #pragma unroll
  for (int ks = 0; ks < 4; ++ks) {
    bf16x8 af = *(const bf16x8*)(zp + ks * 512 + pl * 8);
    const ushort* bb = Bp1 + (size_t)ks * 4096 + lane * 8;
    #pragma unroll
    for (int t = 0; t < 8; ++t)
      acc[t] = __builtin_amdgcn_mfma_f32_16x16x32_bf16(af, *(const bf16x8*)(bb + t * 512), acc[t], 0, 0, 0);
  }
  // ---- final: z2 = relu(acc + bp1); logits = z2 @ Wp2 + bp2; sigmoid ----
  float p0[4] = {0.f, 0.f, 0.f, 0.f}, p1[4] = {0.f, 0.f, 0.f, 0.f};
  #pragma unroll
  for (int t = 0; t < 8; ++t) {
    int c = t * 16 + m;
    float bv = bp1[c];
    float wa = Wp2[(size_t)c * 2], wb = Wp2[(size_t)c * 2 + 1];
    #pragma unroll
    for (int i = 0; i < 4; ++i) {
      float z = fmaxf(acc[t][i] + bv, 0.f);
      p0[i] += z * wa;
      p1[i] += z * wb;
    }
  }
  #pragma unroll
  for (int msk = 1; msk <= 8; msk <<= 1) {
    #pragma unroll
    for (int i = 0; i < 4; ++i) {
      p0[i] += __shfl_xor(p0[i], msk);
      p1[i] += __shfl_xor(p1[i], msk);
    }
  }
  if (m == 0) {
    float c0 = bp2[0], c1 = bp2[1];
    #pragma unroll
    for (int i = 0; i < 4; ++i) {
      int r = pair0 + kg * 4 + i;
      if (r < P) {
        float l0 = p0[i] + c0, l1 = p1[i] + c1;
        op[r] = 1.0f / (1.0f + expf(l0 - l1));
      }
    }
  }
}

// ======================= launch =======================
extern "C" void kernel_launch(void* const* d_in, const int* in_sizes, int n_in,
                              void* d_out, int out_size, void* d_ws, size_t ws_size,
                              hipStream_t stream) {
  const float* x       = (const float*)d_in[0];
  const int*   src     = (const int*)d_in[1];
  const int*   dst     = (const int*)d_in[2];
  const int*   pos_src = (const int*)d_in[3];
  const int*   pos_dst = (const int*)d_in[4];
  const int*   neg_src = (const int*)d_in[5];
  const int*   neg_dst = (const int*)d_in[6];
  const float* Ws0 = (const float*)d_in[7],  *Wn0 = (const float*)d_in[8],  *b0 = (const float*)d_in[9];
  const float* Ws1 = (const float*)d_in[10], *Wn1 = (const float*)d_in[11], *b1 = (const float*)d_in[12];
  const float* Ws2 = (const float*)d_in[13], *Wn2 = (const float*)d_in[14], *b2 = (const float*)d_in[15];
  const float* Wp0 = (const float*)d_in[16], *bp0 = (const float*)d_in[17];
  const float* Wp1 = (const float*)d_in[18], *bp1 = (const float*)d_in[19];
  const float* Wp2 = (const float*)d_in[20], *bp2 = (const float*)d_in[21];
  const int N = in_sizes[0] / D;
  const int E = in_sizes[1];
  const int P = in_sizes[3];
  float* outp = (float*)d_out;

  char* ws = (char*)d_ws;
  size_t off = 0;
  auto alloc = [&](size_t bytes) -> void* {
    void* p = ws + off;
    off += (bytes + 255) & ~(size_t)255;
    return p;
  };
  ushort* xb    = (ushort*)alloc((size_t)N * D * 2);
  ushort* h1    = (ushort*)alloc((size_t)N * D * 2);
  ushort* h2    = (ushort*)alloc((size_t)N * D * 2);
  ushort* hn    = (ushort*)alloc((size_t)N * D * 2);
  ushort* BpL0  = (ushort*)alloc(256 * D * 2);
  ushort* BpL1  = (ushort*)alloc(256 * D * 2);
  ushort* BpL2  = (ushort*)alloc(256 * D * 2);
  ushort* BpP0  = (ushort*)alloc(128 * D * 2);
  ushort* BpP1  = (ushort*)alloc(128 * D * 2);
  int*    deg    = (int*)alloc((size_t)N * 4);
  int*    rowptr = (int*)alloc((size_t)(N + 1) * 4);
  int*    cursor = (int*)alloc((size_t)N * 4);
  int*    part   = (int*)alloc(4096);
  int*    csrc   = (int*)alloc((size_t)E * 4);
  (void)ws_size; (void)n_in; (void)out_size;

  const float pscale = 8.0f / (float)N;
  const int CB = 96;                           // blocks per XCD-part
  const int CE = (E + CB - 1) / CB;            // edges per chunk

  // prep (deg zero + conv + weight pack) — replaces memset+conv+pack launches
  k_prep<<<512, 256, 0, stream>>>(x, xb, Ws0, Wn0, Ws1, Wn1, Ws2, Wn2, Wp0, Wp1,
                                  BpL0, BpL1, BpL2, BpP0, BpP1, deg, N);
  // CSR build
  k_degree_p<<<8 * CB, 256, 0, stream>>>(dst, E, deg, pscale, CE);
  int nb = (N + SCAN_CHUNK - 1) / SCAN_CHUNK;
  k_scan_partial<<<nb, SCAN_T, 0, stream>>>(deg, N, part);
  k_scan_part_ex<<<1, 1024, 0, stream>>>(part, nb);
  k_scan_final<<<nb, SCAN_T, 0, stream>>>(deg, N, part, rowptr, cursor, E);
  k_fill_p<<<8 * CB, 256, 0, stream>>>(src, dst, E, cursor, csrc, pscale, CE);

  int aggb = (N + 15) / 16;      // 4 nodes/wave, 4 waves/block
  int gemb = (N + 63) / 64;
  k_aggregate2<<<aggb, 256, 0, stream>>>(xb, rowptr, csrc, hn, N);
  k_gemm_mfma<<<gemb, 256, 0, stream>>>(xb, hn, BpL0, b0, h1, N, 1);
  k_aggregate2<<<aggb, 256, 0, stream>>>(h1, rowptr, csrc, hn, N);
  k_gemm_mfma<<<gemb, 256, 0, stream>>>(h1, hn, BpL1, b1, h2, N, 1);
  k_aggregate2<<<aggb, 256, 0, stream>>>(h2, rowptr, csrc, hn, N);
  k_gemm_mfma<<<gemb, 256, 0, stream>>>(h2, hn, BpL2, b2, xb, N, 0);

  int pb = (P + 63) / 64;
  k_predict_mfma<<<2 * pb, 256, 0, stream>>>(xb, pos_src, pos_dst, neg_src, neg_dst,
                                             BpP0, bp0, BpP1, bp1, Wp2, bp2, outp, P, pb);
}